// Round 5
// baseline (1276.059 us; speedup 1.0000x reference)
//
#include <hip/hip_runtime.h>
#include <hip/hip_fp16.h>

constexpr int IN_DIM  = 256;
constexpr int HID_DIM = 128;
constexpr int OUT_DIM = 64;
constexpr int NPART   = 8;   // one node-partition per XCD

__device__ __forceinline__ int xcc_id() {
  int x;
  asm volatile("s_getreg_b32 %0, hwreg(HW_REG_XCC_ID)" : "=s"(x));
  return x & 7;
}

// ---------------- degree / CSR build ----------------

__global__ __launch_bounds__(256) void k_zero(int* __restrict__ p, int n) {
  int i = blockIdx.x * 256 + threadIdx.x;
  if (i < n) p[i] = 0;
}

// XCC-pinned count: block reads its REAL XCD id, drains that XCD's chunk queue,
// commits only dsts in partition [xcc*npp, xcc*npp+npp) -> cnt slice stays in
// this XCD's L2 only.
__global__ __launch_bounds__(256) void k_count_q(const int* __restrict__ dst, int E,
                                                 int* __restrict__ cnt, int npp, int nchunks,
                                                 int* __restrict__ qhead) {
  __shared__ int s_c;
  const int xcc = xcc_id();
  const int lo = xcc * npp, hi = lo + npp;
  const int per = (E + nchunks - 1) / nchunks;
  for (;;) {
    __syncthreads();
    if (threadIdx.x == 0) s_c = atomicAdd(&qhead[xcc], 1);
    __syncthreads();
    int c = s_c;
    if (c >= nchunks) break;
    int e0 = c * per, e1 = min(e0 + per, E);
    for (int e = e0 + threadIdx.x; e < e1; e += 256) {
      int d = __builtin_nontemporal_load(&dst[e]);
      if (d >= lo && d < hi) atomicAdd(&cnt[d], 1);
    }
  }
}

// per-1024-element block sums
__global__ __launch_bounds__(256) void k_bsum(const int* __restrict__ cnt, int n,
                                              int* __restrict__ bsum) {
  __shared__ int sh[256];
  int t = threadIdx.x;
  int i0 = blockIdx.x * 1024 + t * 4;
  int s = 0;
#pragma unroll
  for (int j = 0; j < 4; j++) { int i = i0 + j; if (i < n) s += cnt[i]; }
  sh[t] = s; __syncthreads();
  for (int off = 128; off > 0; off >>= 1) {
    if (t < off) sh[t] += sh[t + off];
    __syncthreads();
  }
  if (t == 0) bsum[blockIdx.x] = sh[0];
}

// exclusive scan of block sums (nb <= 256), single block
__global__ void k_bscan(int* __restrict__ bsum, int nb) {
  __shared__ int sh[256];
  int t = threadIdx.x;
  if (t < nb) sh[t] = bsum[t];
  __syncthreads();
  if (t == 0) {
    int run = 0;
    for (int i = 0; i < nb; i++) { int v = sh[i]; sh[i] = run; run += v; }
  }
  __syncthreads();
  if (t < nb) bsum[t] = sh[t];
}

// final: rowptr (exclusive scan), cursor copy, dis = rsqrt(deg+1)
__global__ __launch_bounds__(256) void k_scan_final(
    const int* __restrict__ cnt, int n, const int* __restrict__ bbase,
    int* __restrict__ rowptr, int* __restrict__ pos, float* __restrict__ dis, int E) {
  __shared__ int sh[256];
  int t = threadIdx.x;
  int i0 = blockIdx.x * 1024 + t * 4;
  int c[4]; int s = 0;
#pragma unroll
  for (int j = 0; j < 4; j++) { int i = i0 + j; c[j] = (i < n) ? cnt[i] : 0; s += c[j]; }
  sh[t] = s; __syncthreads();
  for (int off = 1; off < 256; off <<= 1) {
    int add = (t >= off) ? sh[t - off] : 0;
    __syncthreads();
    sh[t] += add;
    __syncthreads();
  }
  int run = bbase[blockIdx.x] + sh[t] - s;  // exclusive prefix for this thread
#pragma unroll
  for (int j = 0; j < 4; j++) {
    int i = i0 + j;
    if (i < n) {
      rowptr[i] = run;
      pos[i] = run;
      dis[i] = rsqrtf((float)c[j] + 1.0f);  // +1 self loop
      run += c[j];
    }
  }
  if (blockIdx.x == 0 && t == 0) rowptr[n] = E;
}

// XCC-pinned fill: partition xcc's col segment (~1.6 MB) + pos cursors are
// written only from this XCD -> single-L2 residency -> ~1x write amplification.
__global__ __launch_bounds__(256) void k_fill_q(const int* __restrict__ src,
                                                const int* __restrict__ dst, int E,
                                                int* __restrict__ pos, int* __restrict__ col,
                                                int npp, int nchunks,
                                                int* __restrict__ qhead) {
  __shared__ int s_c;
  const int xcc = xcc_id();
  const int lo = xcc * npp, hi = lo + npp;
  const int per = (E + nchunks - 1) / nchunks;
  for (;;) {
    __syncthreads();
    if (threadIdx.x == 0) s_c = atomicAdd(&qhead[xcc], 1);
    __syncthreads();
    int c = s_c;
    if (c >= nchunks) break;
    int e0 = c * per, e1 = min(e0 + per, E);
    for (int e = e0 + threadIdx.x; e < e1; e += 256) {
      int d = __builtin_nontemporal_load(&dst[e]);
      if (d >= lo && d < hi) {
        int s = __builtin_nontemporal_load(&src[e]);
        int p = atomicAdd(&pos[d], 1);
        col[p] = s;
      }
    }
  }
}

// ---------------- GEMM: out[r][c] = (half) dis[r] * sum_k A[r][k]*W[k][c] ----------------
// BM=128, BK=32, block=256: 16 col-threads x 16 row-threads, 8 rows x N/16 cols each.
// fp32 compute, fp16 output (output only feeds the gather).

template <int K, int N>
__global__ __launch_bounds__(256) void k_gemm_h(const float* __restrict__ A,
                                                const float* __restrict__ W,
                                                const float* __restrict__ dis,
                                                __half* __restrict__ out, int M) {
  constexpr int CPT = N / 16;  // cols per thread: 8 (N=128) or 4 (N=64)
  __shared__ float Xs[128][33];  // +1 pad: conflict-free column reads
  __shared__ float Ws[32][N];
  const int tid = threadIdx.x;
  const int tx = tid & 15;
  const int ty = tid >> 4;
  const int row0 = blockIdx.x * 128;
  float acc[8][CPT];
#pragma unroll
  for (int i = 0; i < 8; i++)
#pragma unroll
    for (int j = 0; j < CPT; j++) acc[i][j] = 0.f;

  for (int k0 = 0; k0 < K; k0 += 32) {
    __syncthreads();
    // stage X tile: 128x32 floats (1024 float4 / 256 threads = 4 each)
#pragma unroll
    for (int idx = tid; idx < 1024; idx += 256) {
      int fi = idx * 4; int r = fi >> 5; int f = fi & 31;
      int gr = row0 + r; if (gr > M - 1) gr = M - 1;
      const float4 v = *(const float4*)&A[(size_t)gr * K + k0 + f];
      Xs[r][f] = v.x; Xs[r][f + 1] = v.y; Xs[r][f + 2] = v.z; Xs[r][f + 3] = v.w;
    }
    // stage W tile: 32xN floats
#pragma unroll
    for (int idx = tid; idx < (32 * N) / 4; idx += 256) {
      int fi = idx * 4; int wr = fi / N; int wc = fi % N;
      *(float4*)&Ws[wr][wc] = *(const float4*)&W[(size_t)(k0 + wr) * N + wc];
    }
    __syncthreads();
#pragma unroll
    for (int kk = 0; kk < 32; kk++) {
      float xv[8];
#pragma unroll
      for (int i = 0; i < 8; i++) xv[i] = Xs[ty * 8 + i][kk];
      float wv[CPT];
#pragma unroll
      for (int j = 0; j < CPT; j += 4) {
        float4 w4 = *(const float4*)&Ws[kk][tx * CPT + j];
        wv[j] = w4.x; wv[j + 1] = w4.y; wv[j + 2] = w4.z; wv[j + 3] = w4.w;
      }
#pragma unroll
      for (int i = 0; i < 8; i++)
#pragma unroll
        for (int j = 0; j < CPT; j++) acc[i][j] = fmaf(xv[i], wv[j], acc[i][j]);
    }
  }
#pragma unroll
  for (int i = 0; i < 8; i++) {
    int r = row0 + ty * 8 + i;
    if (r < M) {
      float d = dis[r];
      __half tmp[CPT];
#pragma unroll
      for (int j = 0; j < CPT; j++) tmp[j] = __float2half_rn(d * acc[i][j]);
      if (CPT == 8) {
        *(float4*)&out[(size_t)r * N + tx * CPT] = *(const float4*)tmp;
      } else {
        *(float2*)&out[(size_t)r * N + tx * CPT] = *(const float2*)tmp;
      }
    }
  }
}

// ---------------- aggregation: out[v] = act(dv*(g[v] + sum_u g[u]) + b) ----------------
// one wave per node; g stored fp16 (halves gather bytes), fp32 accumulate.

template <int F, bool RELU>
__global__ __launch_bounds__(256) void k_agg(const __half* __restrict__ g,
                                             const int* __restrict__ rowptr,
                                             const int* __restrict__ col,
                                             const float* __restrict__ dis,
                                             const float* __restrict__ bias,
                                             float* __restrict__ out, int n) {
  int lane = threadIdx.x & 63;
  int v = blockIdx.x * 4 + (threadIdx.x >> 6);
  if (v >= n) return;
  int p = rowptr[v], end = rowptr[v + 1];
  float dv = dis[v];
  if (F == 128) {
    float2 f0 = __half22float2(*(const __half2*)&g[(size_t)v * 128 + lane * 2]);
    float ax = f0.x, ay = f0.y;  // self term
    for (; p + 8 <= end; p += 8) {
      int u[8];
#pragma unroll
      for (int j = 0; j < 8; j++) u[j] = __builtin_nontemporal_load(&col[p + j]);
      __half2 t[8];
#pragma unroll
      for (int j = 0; j < 8; j++) t[j] = *(const __half2*)&g[(size_t)u[j] * 128 + lane * 2];
#pragma unroll
      for (int j = 0; j < 8; j++) {
        float2 f = __half22float2(t[j]);
        ax += f.x; ay += f.y;
      }
    }
    for (; p < end; p++) {
      int u = __builtin_nontemporal_load(&col[p]);
      float2 f = __half22float2(*(const __half2*)&g[(size_t)u * 128 + lane * 2]);
      ax += f.x; ay += f.y;
    }
    float ox = fmaf(dv, ax, bias[lane * 2]);
    float oy = fmaf(dv, ay, bias[lane * 2 + 1]);
    if (RELU) { ox = fmaxf(ox, 0.f); oy = fmaxf(oy, 0.f); }
    float2 o; o.x = ox; o.y = oy;
    *(float2*)&out[(size_t)v * 128 + lane * 2] = o;
  } else {
    float acc = __half2float(g[(size_t)v * 64 + lane]);
    for (; p + 8 <= end; p += 8) {
      int u[8];
#pragma unroll
      for (int j = 0; j < 8; j++) u[j] = __builtin_nontemporal_load(&col[p + j]);
      __half t[8];
#pragma unroll
      for (int j = 0; j < 8; j++) t[j] = g[(size_t)u[j] * 64 + lane];
#pragma unroll
      for (int j = 0; j < 8; j++) acc += __half2float(t[j]);
    }
    for (; p < end; p++) {
      int u = __builtin_nontemporal_load(&col[p]);
      acc += __half2float(g[(size_t)u * 64 + lane]);
    }
    float o = fmaf(dv, acc, bias[lane]);
    if (RELU) o = fmaxf(o, 0.f);
    out[(size_t)v * 64 + lane] = o;
  }
}

// ---------------- launch ----------------

extern "C" void kernel_launch(void* const* d_in, const int* in_sizes, int n_in,
                              void* d_out, int out_size, void* d_ws, size_t ws_size,
                              hipStream_t stream) {
  const float* x  = (const float*)d_in[0];
  const int*   ei = (const int*)d_in[1];
  const float* W1 = (const float*)d_in[2];
  const float* b1 = (const float*)d_in[3];
  const float* W2 = (const float*)d_in[4];
  const float* b2 = (const float*)d_in[5];
  const float* W3 = (const float*)d_in[6];
  const float* b3 = (const float*)d_in[7];
  float* outp = (float*)d_out;

  const int N = in_sizes[0] / IN_DIM;   // 100000
  const int E = in_sizes[1] / 2;        // 3200000
  const int* src = ei;
  const int* dst = ei + E;

  char* w = (char*)d_ws;
  auto take = [&](size_t bytes) {
    char* r = w;
    w += (bytes + 255) & ~size_t(255);
    return r;
  };
  float*  dis    = (float*)take((size_t)N * 4);
  int*    cnt    = (int*)take((size_t)(N + 16) * 4);  // cnt[N] + 16 queue heads
  int*    qheads = cnt + N;                            // [0..7] count, [8..15] fill
  int*    rowptr = (int*)take((size_t)(N + 1) * 4);
  int*    pos    = (int*)take((size_t)N * 4);
  int*    bsum   = (int*)take(256 * 4);
  int*    col    = (int*)take((size_t)E * 4);
  __half* gbuf   = (__half*)take((size_t)N * 128 * 2);  // fp16 gather buffer
  float*  bufB   = (float*)take((size_t)N * 128 * 4);   // fp32 agg output

  const int nb = (N + 1023) / 1024;
  const int npp = (N + NPART - 1) / NPART;  // nodes per partition (12500)
  const int nchunks = 2048;                  // edge chunks per XCD queue
  hipLaunchKernelGGL(k_zero, dim3((N + 16 + 255) / 256), dim3(256), 0, stream, cnt, N + 16);
  hipLaunchKernelGGL(k_count_q, dim3(2048), dim3(256), 0, stream, dst, E, cnt, npp, nchunks, qheads);
  hipLaunchKernelGGL(k_bsum, dim3(nb), dim3(256), 0, stream, cnt, N, bsum);
  hipLaunchKernelGGL(k_bscan, dim3(1), dim3(256), 0, stream, bsum, nb);
  hipLaunchKernelGGL(k_scan_final, dim3(nb), dim3(256), 0, stream, cnt, N, bsum, rowptr, pos, dis, E);
  hipLaunchKernelGGL(k_fill_q, dim3(2048), dim3(256), 0, stream, src, dst, E, pos, col, npp, nchunks, qheads + 8);

  const int gb = (N + 127) / 128;
  const int ab = (N + 3) / 4;
  // layer 1: g1 = fp16(dis*(x@W1)) -> agg -> relu -> bufB (fp32)
  hipLaunchKernelGGL((k_gemm_h<256, 128>), dim3(gb), dim3(256), 0, stream, x, W1, dis, gbuf, N);
  hipLaunchKernelGGL((k_agg<128, true>), dim3(ab), dim3(256), 0, stream, gbuf, rowptr, col, dis, b1, bufB, N);
  // layer 2
  hipLaunchKernelGGL((k_gemm_h<128, 128>), dim3(gb), dim3(256), 0, stream, bufB, W2, dis, gbuf, N);
  hipLaunchKernelGGL((k_agg<128, true>), dim3(ab), dim3(256), 0, stream, gbuf, rowptr, col, dis, b2, bufB, N);
  // layer 3 (no relu), output 64-dim straight to d_out (fp32)
  hipLaunchKernelGGL((k_gemm_h<128, 64>), dim3(gb), dim3(256), 0, stream, bufB, W3, dis, gbuf, N);
  hipLaunchKernelGGL((k_agg<64, false>), dim3(ab), dim3(256), 0, stream, gbuf, rowptr, col, dis, b3, outp, N);
}

// Round 6
// 847.353 us; speedup vs baseline: 1.5059x; 1.5059x over previous
//
#include <hip/hip_runtime.h>
#include <hip/hip_fp16.h>

constexpr int IN_DIM  = 256;
constexpr int HID_DIM = 128;
constexpr int OUT_DIM = 64;

constexpr int NPB_SHIFT = 8;          // 256 nodes per bucket
constexpr int NPB   = 1 << NPB_SHIFT;
constexpr int NBMAX = 512;            // max buckets supported in LDS tables
constexpr int CHUNK = 4096;           // edges per binning block
constexpr int CAP_B = 12288;          // LDS col-stage capacity (48 KB); mean 8184, +45 sigma

// ---------------- misc ----------------

__global__ __launch_bounds__(256) void k_zero(int* __restrict__ p, int n) {
  int i = blockIdx.x * 256 + threadIdx.x;
  if (i < n) p[i] = 0;
}

// ---------------- CSR build via bucketed counting sort ----------------

// Per-block LDS histogram of dst buckets -> global bucket sizes.
__global__ __launch_bounds__(256) void k_hist(const int* __restrict__ dst, int E, int NB,
                                              int* __restrict__ bsize) {
  __shared__ int h[NBMAX];
  for (int i = threadIdx.x; i < NB; i += 256) h[i] = 0;
  __syncthreads();
  int e0 = blockIdx.x * CHUNK;
  int e1 = min(e0 + CHUNK, E);
  for (int e = e0 + threadIdx.x; e < e1; e += 256) {
    int d = __builtin_nontemporal_load(&dst[e]);
    atomicAdd(&h[d >> NPB_SHIFT], 1);
  }
  __syncthreads();
  for (int b = threadIdx.x; b < NB; b += 256) {
    int c = h[b];
    if (c) atomicAdd(&bsize[b], c);
  }
}

// Exclusive scan of bucket sizes (NB <= 512), one block.
__global__ __launch_bounds__(512) void k_scanb(const int* __restrict__ bsize, int NB, int E,
                                               int* __restrict__ boff, int* __restrict__ gcur) {
  __shared__ int sh[NBMAX + 1];
  for (int i = threadIdx.x; i < NB; i += 512) sh[i] = bsize[i];
  __syncthreads();
  if (threadIdx.x == 0) {
    int run = 0;
    for (int b = 0; b < NB; b++) { int v = sh[b]; sh[b] = run; run += v; }
    sh[NB] = run;
  }
  __syncthreads();
  for (int i = threadIdx.x; i < NB; i += 512) { boff[i] = sh[i]; gcur[i] = sh[i]; }
  if (threadIdx.x == 0) boff[NB] = sh[NB];
}

// Local counting sort of a 4096-edge chunk in LDS, then coalesced run-append
// into global bucket regions. All scattered stores hit LDS, never HBM.
__global__ __launch_bounds__(256) void k_binA(const int* __restrict__ src,
                                              const int* __restrict__ dst, int E, int NB,
                                              int* __restrict__ gcur,
                                              unsigned long long* __restrict__ bin) {
  __shared__ unsigned long long sbuf[CHUNK];  // 32 KB
  __shared__ int h[NBMAX], lofs[NBMAX], wofs[NBMAX], hcur[NBMAX];
  for (int i = threadIdx.x; i < NB; i += 256) h[i] = 0;
  __syncthreads();
  int e0 = blockIdx.x * CHUNK;
  int e1 = min(e0 + CHUNK, E);
  for (int e = e0 + threadIdx.x; e < e1; e += 256) {
    int d = __builtin_nontemporal_load(&dst[e]);
    atomicAdd(&h[d >> NPB_SHIFT], 1);
  }
  __syncthreads();
  // global run reservation (parallel) + local exclusive scan (thread 0, LDS-resident)
  for (int b = threadIdx.x; b < NB; b += 256) {
    int c = h[b];
    if (c) wofs[b] = atomicAdd(&gcur[b], c);
  }
  if (threadIdx.x == 0) {
    int run = 0;
    for (int b = 0; b < NB; b++) { lofs[b] = run; run += h[b]; }
  }
  __syncthreads();
  for (int b = threadIdx.x; b < NB; b += 256) hcur[b] = lofs[b];
  __syncthreads();
  // scatter chunk into LDS, sorted by bucket
  for (int e = e0 + threadIdx.x; e < e1; e += 256) {
    int d = dst[e];  // L1/L2-hot re-read
    int s = src[e];
    int b = d >> NPB_SHIFT;
    int p = atomicAdd(&hcur[b], 1);
    sbuf[p] = ((unsigned long long)(unsigned)d << 32) | (unsigned)s;
  }
  __syncthreads();
  // coalesced run copy-out
  int total = e1 - e0;
  for (int i = threadIdx.x; i < total; i += 256) {
    unsigned long long v = sbuf[i];
    int b = (int)(v >> 32) >> NPB_SHIFT;
    bin[(size_t)wofs[b] + (i - lofs[b])] = v;
  }
}

// One block per bucket: per-node count + scan in LDS -> rowptr/dis; scatter src
// into LDS col stage at exact final positions; coalesced copy to global col.
__global__ __launch_bounds__(256) void k_passB(const unsigned long long* __restrict__ bin,
                                               const int* __restrict__ boff, int NB, int N, int E,
                                               int* __restrict__ rowptr, float* __restrict__ dis,
                                               int* __restrict__ col) {
  __shared__ unsigned int colbuf[CAP_B];  // 48 KB
  __shared__ int lcnt[NPB], lofs2[NPB + 1], lpos[NPB];
  int b = blockIdx.x;
  int lo = b << NPB_SHIFT;
  int e0 = boff[b], e1 = boff[b + 1];
  int tot = e1 - e0;
  if (threadIdx.x < NPB) lcnt[threadIdx.x] = 0;
  __syncthreads();
  for (int i = threadIdx.x; i < tot; i += 256) {
    unsigned long long v = bin[(size_t)e0 + i];
    atomicAdd(&lcnt[(int)(v >> 32) & (NPB - 1)], 1);
  }
  __syncthreads();
  if (threadIdx.x == 0) {
    int run = 0;
    for (int i = 0; i < NPB; i++) { lofs2[i] = run; run += lcnt[i]; }
    lofs2[NPB] = run;
  }
  __syncthreads();
  if (threadIdx.x < NPB) {
    int node = lo + threadIdx.x;
    if (node < N) {
      rowptr[node] = e0 + lofs2[threadIdx.x];
      dis[node] = rsqrtf((float)lcnt[threadIdx.x] + 1.0f);  // +1 self loop
    }
    lpos[threadIdx.x] = lofs2[threadIdx.x];
  }
  __syncthreads();
  for (int i = threadIdx.x; i < tot; i += 256) {
    unsigned long long v = bin[(size_t)e0 + i];
    int idx = (int)(v >> 32) & (NPB - 1);
    int p = atomicAdd(&lpos[idx], 1);
    unsigned int s = (unsigned int)v;
    if (p < CAP_B) colbuf[p] = s;
    else col[(size_t)e0 + p] = s;  // overflow fallback (position still exact)
  }
  __syncthreads();
  int cp = min(tot, CAP_B);
  for (int i = threadIdx.x; i < cp; i += 256)
    __builtin_nontemporal_store(colbuf[i], (unsigned int*)&col[(size_t)e0 + i]);
  if (b == 0 && threadIdx.x == 0) rowptr[N] = E;
}

// ---------------- GEMM: out[r][c] = (half) dis[r] * sum_k A[r][k]*W[k][c] ----------------
// BM=128, BK=32, block=256: 16 col-threads x 16 row-threads, 8 rows x N/16 cols each.
// fp32 compute, fp16 output (output only feeds the gather).

template <int K, int N>
__global__ __launch_bounds__(256) void k_gemm_h(const float* __restrict__ A,
                                                const float* __restrict__ W,
                                                const float* __restrict__ dis,
                                                __half* __restrict__ out, int M) {
  constexpr int CPT = N / 16;  // cols per thread: 8 (N=128) or 4 (N=64)
  __shared__ float Xs[128][33];  // +1 pad: conflict-free column reads
  __shared__ float Ws[32][N];
  const int tid = threadIdx.x;
  const int tx = tid & 15;
  const int ty = tid >> 4;
  const int row0 = blockIdx.x * 128;
  float acc[8][CPT];
#pragma unroll
  for (int i = 0; i < 8; i++)
#pragma unroll
    for (int j = 0; j < CPT; j++) acc[i][j] = 0.f;

  for (int k0 = 0; k0 < K; k0 += 32) {
    __syncthreads();
#pragma unroll
    for (int idx = tid; idx < 1024; idx += 256) {
      int fi = idx * 4; int r = fi >> 5; int f = fi & 31;
      int gr = row0 + r; if (gr > M - 1) gr = M - 1;
      const float4 v = *(const float4*)&A[(size_t)gr * K + k0 + f];
      Xs[r][f] = v.x; Xs[r][f + 1] = v.y; Xs[r][f + 2] = v.z; Xs[r][f + 3] = v.w;
    }
#pragma unroll
    for (int idx = tid; idx < (32 * N) / 4; idx += 256) {
      int fi = idx * 4; int wr = fi / N; int wc = fi % N;
      *(float4*)&Ws[wr][wc] = *(const float4*)&W[(size_t)(k0 + wr) * N + wc];
    }
    __syncthreads();
#pragma unroll
    for (int kk = 0; kk < 32; kk++) {
      float xv[8];
#pragma unroll
      for (int i = 0; i < 8; i++) xv[i] = Xs[ty * 8 + i][kk];
      float wv[CPT];
#pragma unroll
      for (int j = 0; j < CPT; j += 4) {
        float4 w4 = *(const float4*)&Ws[kk][tx * CPT + j];
        wv[j] = w4.x; wv[j + 1] = w4.y; wv[j + 2] = w4.z; wv[j + 3] = w4.w;
      }
#pragma unroll
      for (int i = 0; i < 8; i++)
#pragma unroll
        for (int j = 0; j < CPT; j++) acc[i][j] = fmaf(xv[i], wv[j], acc[i][j]);
    }
  }
#pragma unroll
  for (int i = 0; i < 8; i++) {
    int r = row0 + ty * 8 + i;
    if (r < M) {
      float d = dis[r];
      __half tmp[CPT];
#pragma unroll
      for (int j = 0; j < CPT; j++) tmp[j] = __float2half_rn(d * acc[i][j]);
      if (CPT == 8) {
        *(float4*)&out[(size_t)r * N + tx * CPT] = *(const float4*)tmp;
      } else {
        *(float2*)&out[(size_t)r * N + tx * CPT] = *(const float2*)tmp;
      }
    }
  }
}

// ---------------- aggregation: out[v] = act(dv*(g[v] + sum_u g[u]) + b) ----------------
// one wave per node; g stored fp16 (halves gather bytes), fp32 accumulate.

template <int F, bool RELU>
__global__ __launch_bounds__(256) void k_agg(const __half* __restrict__ g,
                                             const int* __restrict__ rowptr,
                                             const int* __restrict__ col,
                                             const float* __restrict__ dis,
                                             const float* __restrict__ bias,
                                             float* __restrict__ out, int n) {
  int lane = threadIdx.x & 63;
  int v = blockIdx.x * 4 + (threadIdx.x >> 6);
  if (v >= n) return;
  int p = rowptr[v], end = rowptr[v + 1];
  float dv = dis[v];
  if (F == 128) {
    float2 f0 = __half22float2(*(const __half2*)&g[(size_t)v * 128 + lane * 2]);
    float ax = f0.x, ay = f0.y;  // self term
    for (; p + 8 <= end; p += 8) {
      int u[8];
#pragma unroll
      for (int j = 0; j < 8; j++) u[j] = __builtin_nontemporal_load(&col[p + j]);
      __half2 t[8];
#pragma unroll
      for (int j = 0; j < 8; j++) t[j] = *(const __half2*)&g[(size_t)u[j] * 128 + lane * 2];
#pragma unroll
      for (int j = 0; j < 8; j++) {
        float2 f = __half22float2(t[j]);
        ax += f.x; ay += f.y;
      }
    }
    for (; p < end; p++) {
      int u = __builtin_nontemporal_load(&col[p]);
      float2 f = __half22float2(*(const __half2*)&g[(size_t)u * 128 + lane * 2]);
      ax += f.x; ay += f.y;
    }
    float ox = fmaf(dv, ax, bias[lane * 2]);
    float oy = fmaf(dv, ay, bias[lane * 2 + 1]);
    if (RELU) { ox = fmaxf(ox, 0.f); oy = fmaxf(oy, 0.f); }
    float2 o; o.x = ox; o.y = oy;
    *(float2*)&out[(size_t)v * 128 + lane * 2] = o;
  } else {
    float acc = __half2float(g[(size_t)v * 64 + lane]);
    for (; p + 8 <= end; p += 8) {
      int u[8];
#pragma unroll
      for (int j = 0; j < 8; j++) u[j] = __builtin_nontemporal_load(&col[p + j]);
      __half t[8];
#pragma unroll
      for (int j = 0; j < 8; j++) t[j] = g[(size_t)u[j] * 64 + lane];
#pragma unroll
      for (int j = 0; j < 8; j++) acc += __half2float(t[j]);
    }
    for (; p < end; p++) {
      int u = __builtin_nontemporal_load(&col[p]);
      acc += __half2float(g[(size_t)u * 64 + lane]);
    }
    float o = fmaf(dv, acc, bias[lane]);
    if (RELU) o = fmaxf(o, 0.f);
    out[(size_t)v * 64 + lane] = o;
  }
}

// ---------------- launch ----------------

extern "C" void kernel_launch(void* const* d_in, const int* in_sizes, int n_in,
                              void* d_out, int out_size, void* d_ws, size_t ws_size,
                              hipStream_t stream) {
  const float* x  = (const float*)d_in[0];
  const int*   ei = (const int*)d_in[1];
  const float* W1 = (const float*)d_in[2];
  const float* b1 = (const float*)d_in[3];
  const float* W2 = (const float*)d_in[4];
  const float* b2 = (const float*)d_in[5];
  const float* W3 = (const float*)d_in[6];
  const float* b3 = (const float*)d_in[7];
  float* outp = (float*)d_out;

  const int N = in_sizes[0] / IN_DIM;   // 100000
  const int E = in_sizes[1] / 2;        // 3200000
  const int* src = ei;
  const int* dst = ei + E;
  const int NB = (N + NPB - 1) >> NPB_SHIFT;  // 391 buckets

  char* w = (char*)d_ws;
  auto take = [&](size_t bytes) {
    char* r = w;
    w += (bytes + 255) & ~size_t(255);
    return r;
  };
  float*  dis    = (float*)take((size_t)N * 4);
  int*    rowptr = (int*)take((size_t)(N + 1) * 4);
  int*    bsize  = (int*)take((size_t)NB * 4);
  int*    boff   = (int*)take((size_t)(NB + 1) * 4);
  int*    gcur   = (int*)take((size_t)NB * 4);
  int*    col    = (int*)take((size_t)E * 4);
  unsigned long long* bin = (unsigned long long*)take((size_t)E * 8);
  __half* gbuf   = (__half*)take((size_t)N * 128 * 2);  // fp16 gather buffer
  float*  bufB   = (float*)take((size_t)N * 128 * 4);   // fp32 agg output

  const int cb = (E + CHUNK - 1) / CHUNK;  // 782 binning blocks
  hipLaunchKernelGGL(k_zero, dim3((NB + 255) / 256), dim3(256), 0, stream, bsize, NB);
  hipLaunchKernelGGL(k_hist, dim3(cb), dim3(256), 0, stream, dst, E, NB, bsize);
  hipLaunchKernelGGL(k_scanb, dim3(1), dim3(512), 0, stream, bsize, NB, E, boff, gcur);
  hipLaunchKernelGGL(k_binA, dim3(cb), dim3(256), 0, stream, src, dst, E, NB, gcur, bin);
  hipLaunchKernelGGL(k_passB, dim3(NB), dim3(256), 0, stream, bin, boff, NB, N, E, rowptr, dis, col);

  const int gb = (N + 127) / 128;
  const int ab = (N + 3) / 4;
  // layer 1: g1 = fp16(dis*(x@W1)) -> agg -> relu -> bufB (fp32)
  hipLaunchKernelGGL((k_gemm_h<256, 128>), dim3(gb), dim3(256), 0, stream, x, W1, dis, gbuf, N);
  hipLaunchKernelGGL((k_agg<128, true>), dim3(ab), dim3(256), 0, stream, gbuf, rowptr, col, dis, b1, bufB, N);
  // layer 2
  hipLaunchKernelGGL((k_gemm_h<128, 128>), dim3(gb), dim3(256), 0, stream, bufB, W2, dis, gbuf, N);
  hipLaunchKernelGGL((k_agg<128, true>), dim3(ab), dim3(256), 0, stream, gbuf, rowptr, col, dis, b2, bufB, N);
  // layer 3 (no relu), output 64-dim straight to d_out (fp32)
  hipLaunchKernelGGL((k_gemm_h<128, 64>), dim3(gb), dim3(256), 0, stream, bufB, W3, dis, gbuf, N);
  hipLaunchKernelGGL((k_agg<64, false>), dim3(ab), dim3(256), 0, stream, gbuf, rowptr, col, dis, b3, outp, N);
}

// Round 7
// 714.120 us; speedup vs baseline: 1.7869x; 1.1866x over previous
//
#include <hip/hip_runtime.h>
#include <hip/hip_fp16.h>

constexpr int IN_DIM  = 256;
constexpr int HID_DIM = 128;
constexpr int OUT_DIM = 64;

constexpr int NPB_SHIFT = 8;          // 256 nodes per bucket
constexpr int NPB   = 1 << NPB_SHIFT;
constexpr int NBMAX = 512;            // max buckets supported in LDS tables
constexpr int CHUNK = 4096;           // edges per binning block
constexpr int CAP_B = 12288;          // LDS col-stage capacity (48 KB)

typedef _Float16 half8 __attribute__((ext_vector_type(8)));
typedef float floatx4 __attribute__((ext_vector_type(4)));

// ---------------- misc ----------------

__global__ __launch_bounds__(256) void k_zero(int* __restrict__ p, int n) {
  int i = blockIdx.x * 256 + threadIdx.x;
  if (i < n) p[i] = 0;
}

// ---------------- CSR build via bucketed counting sort ----------------

__global__ __launch_bounds__(256) void k_hist(const int* __restrict__ dst, int E, int NB,
                                              int* __restrict__ bsize) {
  __shared__ int h[NBMAX];
  for (int i = threadIdx.x; i < NB; i += 256) h[i] = 0;
  __syncthreads();
  int e0 = blockIdx.x * CHUNK;
  int e1 = min(e0 + CHUNK, E);
  for (int e = e0 + threadIdx.x; e < e1; e += 256) {
    int d = __builtin_nontemporal_load(&dst[e]);
    atomicAdd(&h[d >> NPB_SHIFT], 1);
  }
  __syncthreads();
  for (int b = threadIdx.x; b < NB; b += 256) {
    int c = h[b];
    if (c) atomicAdd(&bsize[b], c);
  }
}

__global__ __launch_bounds__(512) void k_scanb(const int* __restrict__ bsize, int NB, int E,
                                               int* __restrict__ boff, int* __restrict__ gcur) {
  __shared__ int sh[NBMAX + 1];
  for (int i = threadIdx.x; i < NB; i += 512) sh[i] = bsize[i];
  __syncthreads();
  if (threadIdx.x == 0) {
    int run = 0;
    for (int b = 0; b < NB; b++) { int v = sh[b]; sh[b] = run; run += v; }
    sh[NB] = run;
  }
  __syncthreads();
  for (int i = threadIdx.x; i < NB; i += 512) { boff[i] = sh[i]; gcur[i] = sh[i]; }
  if (threadIdx.x == 0) boff[NB] = sh[NB];
}

__global__ __launch_bounds__(256) void k_binA(const int* __restrict__ src,
                                              const int* __restrict__ dst, int E, int NB,
                                              int* __restrict__ gcur,
                                              unsigned long long* __restrict__ bin) {
  __shared__ unsigned long long sbuf[CHUNK];  // 32 KB
  __shared__ int h[NBMAX], lofs[NBMAX], wofs[NBMAX], hcur[NBMAX];
  for (int i = threadIdx.x; i < NB; i += 256) h[i] = 0;
  __syncthreads();
  int e0 = blockIdx.x * CHUNK;
  int e1 = min(e0 + CHUNK, E);
  for (int e = e0 + threadIdx.x; e < e1; e += 256) {
    int d = __builtin_nontemporal_load(&dst[e]);
    atomicAdd(&h[d >> NPB_SHIFT], 1);
  }
  __syncthreads();
  for (int b = threadIdx.x; b < NB; b += 256) {
    int c = h[b];
    if (c) wofs[b] = atomicAdd(&gcur[b], c);
  }
  if (threadIdx.x == 0) {
    int run = 0;
    for (int b = 0; b < NB; b++) { lofs[b] = run; run += h[b]; }
  }
  __syncthreads();
  for (int b = threadIdx.x; b < NB; b += 256) hcur[b] = lofs[b];
  __syncthreads();
  for (int e = e0 + threadIdx.x; e < e1; e += 256) {
    int d = dst[e];
    int s = src[e];
    int b = d >> NPB_SHIFT;
    int p = atomicAdd(&hcur[b], 1);
    sbuf[p] = ((unsigned long long)(unsigned)d << 32) | (unsigned)s;
  }
  __syncthreads();
  int total = e1 - e0;
  for (int i = threadIdx.x; i < total; i += 256) {
    unsigned long long v = sbuf[i];
    int b = (int)(v >> 32) >> NPB_SHIFT;
    bin[(size_t)wofs[b] + (i - lofs[b])] = v;
  }
}

__global__ __launch_bounds__(256) void k_passB(const unsigned long long* __restrict__ bin,
                                               const int* __restrict__ boff, int NB, int N, int E,
                                               int* __restrict__ rowptr, float* __restrict__ dis,
                                               int* __restrict__ col) {
  __shared__ unsigned int colbuf[CAP_B];  // 48 KB
  __shared__ int lcnt[NPB], lofs2[NPB + 1], lpos[NPB];
  int b = blockIdx.x;
  int lo = b << NPB_SHIFT;
  int e0 = boff[b], e1 = boff[b + 1];
  int tot = e1 - e0;
  if (threadIdx.x < NPB) lcnt[threadIdx.x] = 0;
  __syncthreads();
  for (int i = threadIdx.x; i < tot; i += 256) {
    unsigned long long v = bin[(size_t)e0 + i];
    atomicAdd(&lcnt[(int)(v >> 32) & (NPB - 1)], 1);
  }
  __syncthreads();
  if (threadIdx.x == 0) {
    int run = 0;
    for (int i = 0; i < NPB; i++) { lofs2[i] = run; run += lcnt[i]; }
    lofs2[NPB] = run;
  }
  __syncthreads();
  if (threadIdx.x < NPB) {
    int node = lo + threadIdx.x;
    if (node < N) {
      rowptr[node] = e0 + lofs2[threadIdx.x];
      dis[node] = rsqrtf((float)lcnt[threadIdx.x] + 1.0f);  // +1 self loop
    }
    lpos[threadIdx.x] = lofs2[threadIdx.x];
  }
  __syncthreads();
  for (int i = threadIdx.x; i < tot; i += 256) {
    unsigned long long v = bin[(size_t)e0 + i];
    int idx = (int)(v >> 32) & (NPB - 1);
    int p = atomicAdd(&lpos[idx], 1);
    unsigned int s = (unsigned int)v;
    if (p < CAP_B) colbuf[p] = s;
    else col[(size_t)e0 + p] = s;
  }
  __syncthreads();
  int cp = min(tot, CAP_B);
  for (int i = threadIdx.x; i < cp; i += 256)
    __builtin_nontemporal_store(colbuf[i], (unsigned int*)&col[(size_t)e0 + i]);
  if (b == 0 && threadIdx.x == 0) rowptr[N] = E;
}

// ---------------- W pre-pack into MFMA B-fragment order (fp16) ----------------
// B-frag for 16x16x32_f16: lane holds B[k = (lane>>4)*8 + j][n = lane&15].
// Wp flat index: ((ct*(K/32) + ks)*64 + lane)*8 + j, ct = n>>4, ks = k>>5.

template <int K, int N>
__global__ __launch_bounds__(256) void k_packW(const float* __restrict__ W,
                                               _Float16* __restrict__ Wp) {
  int idx = blockIdx.x * 256 + threadIdx.x;
  if (idx >= K * N) return;
  int k = idx / N, n = idx % N;
  int ct = n >> 4, ks = k >> 5, q = (k >> 3) & 3, j = k & 7;
  int lane = (n & 15) + (q << 4);
  Wp[((((size_t)ct * (K / 32) + ks) * 64 + lane) << 3) + j] = (_Float16)W[idx];
}

// ---------------- MFMA GEMM: out[r][c] = fp16(dis[r] * sum_k A[r][k]*W[k][c]) --------
// No LDS. Block = 4 waves; wave w computes rows [blk*64 + w*16, +16) x all N cols.
// A-fragments loaded straight from global (coalesced: 16 rows x contiguous chunks);
// B-fragments from pre-packed Wp (one dwordx4/lane, L2-resident).

template <int K, int N, typename AT>
__global__ __launch_bounds__(256) void k_gemm_mfma(const AT* __restrict__ A,
                                                   const _Float16* __restrict__ Wp,
                                                   const float* __restrict__ dis,
                                                   __half* __restrict__ out, int M) {
  constexpr int CT = N / 16;   // 16-col tiles
  constexpr int KS = K / 32;   // 32-k steps
  const int wave = threadIdx.x >> 6, lane = threadIdx.x & 63;
  const int q = lane >> 4, mlane = lane & 15;
  const int row0 = blockIdx.x * 64 + wave * 16;
  int arow = row0 + mlane;
  if (arow > M - 1) arow = M - 1;  // clamp (dup row, stores guarded)

  floatx4 acc[CT];
#pragma unroll
  for (int c = 0; c < CT; c++) acc[c] = (floatx4){0.f, 0.f, 0.f, 0.f};

#pragma unroll
  for (int ks = 0; ks < KS; ks++) {
    half8 a;
    if constexpr (sizeof(AT) == 4) {
      const float* ap = &A[(size_t)arow * K + ks * 32 + q * 8];
      float4 f0 = *(const float4*)ap;
      float4 f1 = *(const float4*)(ap + 4);
      a[0] = (_Float16)f0.x; a[1] = (_Float16)f0.y;
      a[2] = (_Float16)f0.z; a[3] = (_Float16)f0.w;
      a[4] = (_Float16)f1.x; a[5] = (_Float16)f1.y;
      a[6] = (_Float16)f1.z; a[7] = (_Float16)f1.w;
    } else {
      a = *(const half8*)&A[(size_t)arow * K + ks * 32 + q * 8];
    }
#pragma unroll
    for (int c = 0; c < CT; c++) {
      half8 b = *(const half8*)&Wp[((((size_t)c * KS) + ks) * 64 + lane) << 3];
      acc[c] = __builtin_amdgcn_mfma_f32_16x16x32_f16(a, b, acc[c], 0, 0, 0);
    }
  }

  // C/D layout: col = lane&15 (+ct*16), row = q*4 + r
  float dv[4]; int orow[4];
#pragma unroll
  for (int r = 0; r < 4; r++) {
    orow[r] = row0 + q * 4 + r;
    dv[r] = (orow[r] < M) ? dis[orow[r]] : 0.f;
  }
#pragma unroll
  for (int c = 0; c < CT; c++) {
    int cl = c * 16 + mlane;
#pragma unroll
    for (int r = 0; r < 4; r++)
      if (orow[r] < M)
        out[(size_t)orow[r] * N + cl] = __float2half_rn(dv[r] * acc[c][r]);
  }
}

// ---------------- aggregation: out[v] = act(dv*(g[v] + sum_u g[u]) + b) ----------------
// one wave per node; g fp16 (halves gather bytes), fp32 accumulate.
// HOUT: __half (feeds next GEMM) or float (final output).

template <int F, bool RELU, typename HOUT>
__global__ __launch_bounds__(256) void k_agg(const __half* __restrict__ g,
                                             const int* __restrict__ rowptr,
                                             const int* __restrict__ col,
                                             const float* __restrict__ dis,
                                             const float* __restrict__ bias,
                                             HOUT* __restrict__ out, int n) {
  int lane = threadIdx.x & 63;
  int v = blockIdx.x * 4 + (threadIdx.x >> 6);
  if (v >= n) return;
  int p = rowptr[v], end = rowptr[v + 1];
  float dv = dis[v];
  if (F == 128) {
    float2 f0 = __half22float2(*(const __half2*)&g[(size_t)v * 128 + lane * 2]);
    float ax = f0.x, ay = f0.y;  // self term
    for (; p + 8 <= end; p += 8) {
      int u[8];
#pragma unroll
      for (int j = 0; j < 8; j++) u[j] = __builtin_nontemporal_load(&col[p + j]);
      __half2 t[8];
#pragma unroll
      for (int j = 0; j < 8; j++) t[j] = *(const __half2*)&g[(size_t)u[j] * 128 + lane * 2];
#pragma unroll
      for (int j = 0; j < 8; j++) {
        float2 f = __half22float2(t[j]);
        ax += f.x; ay += f.y;
      }
    }
    for (; p < end; p++) {
      int u = __builtin_nontemporal_load(&col[p]);
      float2 f = __half22float2(*(const __half2*)&g[(size_t)u * 128 + lane * 2]);
      ax += f.x; ay += f.y;
    }
    float ox = fmaf(dv, ax, bias[lane * 2]);
    float oy = fmaf(dv, ay, bias[lane * 2 + 1]);
    if (RELU) { ox = fmaxf(ox, 0.f); oy = fmaxf(oy, 0.f); }
    if constexpr (sizeof(HOUT) == 2) {
      *(__half2*)&out[(size_t)v * 128 + lane * 2] = __float22half2_rn(make_float2(ox, oy));
    } else {
      float2 o; o.x = ox; o.y = oy;
      *(float2*)&out[(size_t)v * 128 + lane * 2] = o;
    }
  } else {
    float acc = __half2float(g[(size_t)v * 64 + lane]);
    for (; p + 8 <= end; p += 8) {
      int u[8];
#pragma unroll
      for (int j = 0; j < 8; j++) u[j] = __builtin_nontemporal_load(&col[p + j]);
      __half t[8];
#pragma unroll
      for (int j = 0; j < 8; j++) t[j] = g[(size_t)u[j] * 64 + lane];
#pragma unroll
      for (int j = 0; j < 8; j++) acc += __half2float(t[j]);
    }
    for (; p < end; p++) {
      int u = __builtin_nontemporal_load(&col[p]);
      acc += __half2float(g[(size_t)u * 64 + lane]);
    }
    float o = fmaf(dv, acc, bias[lane]);
    if (RELU) o = fmaxf(o, 0.f);
    out[(size_t)v * 64 + lane] = (HOUT)o;
  }
}

// ---------------- launch ----------------

extern "C" void kernel_launch(void* const* d_in, const int* in_sizes, int n_in,
                              void* d_out, int out_size, void* d_ws, size_t ws_size,
                              hipStream_t stream) {
  const float* x  = (const float*)d_in[0];
  const int*   ei = (const int*)d_in[1];
  const float* W1 = (const float*)d_in[2];
  const float* b1 = (const float*)d_in[3];
  const float* W2 = (const float*)d_in[4];
  const float* b2 = (const float*)d_in[5];
  const float* W3 = (const float*)d_in[6];
  const float* b3 = (const float*)d_in[7];
  float* outp = (float*)d_out;

  const int N = in_sizes[0] / IN_DIM;   // 100000
  const int E = in_sizes[1] / 2;        // 3200000
  const int* src = ei;
  const int* dst = ei + E;
  const int NB = (N + NPB - 1) >> NPB_SHIFT;  // 391 buckets

  char* w = (char*)d_ws;
  auto take = [&](size_t bytes) {
    char* r = w;
    w += (bytes + 255) & ~size_t(255);
    return r;
  };
  float*  dis    = (float*)take((size_t)N * 4);
  int*    rowptr = (int*)take((size_t)(N + 1) * 4);
  int*    bsize  = (int*)take((size_t)NB * 4);
  int*    boff   = (int*)take((size_t)(NB + 1) * 4);
  int*    gcur   = (int*)take((size_t)NB * 4);
  int*    col    = (int*)take((size_t)E * 4);
  unsigned long long* bin = (unsigned long long*)take((size_t)E * 8);
  _Float16* Wp1  = (_Float16*)take((size_t)IN_DIM * HID_DIM * 2);
  _Float16* Wp2  = (_Float16*)take((size_t)HID_DIM * HID_DIM * 2);
  _Float16* Wp3  = (_Float16*)take((size_t)HID_DIM * OUT_DIM * 2);
  __half* gbuf   = (__half*)take((size_t)N * 128 * 2);  // GEMM out / gather buffer
  __half* bufH   = (__half*)take((size_t)N * 128 * 2);  // agg out (next GEMM A)

  const int cb = (E + CHUNK - 1) / CHUNK;
  hipLaunchKernelGGL(k_zero, dim3((NB + 255) / 256), dim3(256), 0, stream, bsize, NB);
  hipLaunchKernelGGL(k_hist, dim3(cb), dim3(256), 0, stream, dst, E, NB, bsize);
  hipLaunchKernelGGL(k_scanb, dim3(1), dim3(512), 0, stream, bsize, NB, E, boff, gcur);
  hipLaunchKernelGGL(k_binA, dim3(cb), dim3(256), 0, stream, src, dst, E, NB, gcur, bin);
  hipLaunchKernelGGL(k_passB, dim3(NB), dim3(256), 0, stream, bin, boff, NB, N, E, rowptr, dis, col);

  hipLaunchKernelGGL((k_packW<IN_DIM, HID_DIM>), dim3((IN_DIM * HID_DIM + 255) / 256), dim3(256), 0, stream, W1, Wp1);
  hipLaunchKernelGGL((k_packW<HID_DIM, HID_DIM>), dim3((HID_DIM * HID_DIM + 255) / 256), dim3(256), 0, stream, W2, Wp2);
  hipLaunchKernelGGL((k_packW<HID_DIM, OUT_DIM>), dim3((HID_DIM * OUT_DIM + 255) / 256), dim3(256), 0, stream, W3, Wp3);

  const int gb = (N + 63) / 64;
  const int ab = (N + 3) / 4;
  // layer 1: gbuf = fp16(dis*(x@W1)) -> agg+relu -> bufH (fp16)
  hipLaunchKernelGGL((k_gemm_mfma<IN_DIM, HID_DIM, float>), dim3(gb), dim3(256), 0, stream, x, Wp1, dis, gbuf, N);
  hipLaunchKernelGGL((k_agg<128, true, __half>), dim3(ab), dim3(256), 0, stream, gbuf, rowptr, col, dis, b1, bufH, N);
  // layer 2
  hipLaunchKernelGGL((k_gemm_mfma<HID_DIM, HID_DIM, __half>), dim3(gb), dim3(256), 0, stream, bufH, Wp2, dis, gbuf, N);
  hipLaunchKernelGGL((k_agg<128, true, __half>), dim3(ab), dim3(256), 0, stream, gbuf, rowptr, col, dis, b2, bufH, N);
  // layer 3 (no relu), 64-dim, fp32 straight to d_out
  hipLaunchKernelGGL((k_gemm_mfma<HID_DIM, OUT_DIM, __half>), dim3(gb), dim3(256), 0, stream, bufH, Wp3, dis, gbuf, N);
  hipLaunchKernelGGL((k_agg<64, false, float>), dim3(ab), dim3(256), 0, stream, gbuf, rowptr, col, dis, b3, outp, N);
}